// Round 1
// baseline (204.984 us; speedup 1.0000x reference)
//
#include <hip/hip_runtime.h>
#include <hip/hip_fp16.h>

typedef _Float16 f16;
typedef __attribute__((ext_vector_type(8))) _Float16 f16x8;
typedef __attribute__((ext_vector_type(2))) _Float16 f16x2;
typedef __attribute__((ext_vector_type(4))) float f32x4;

#define B_SZ 16
#define T_SZ 2048
#define DIN 512
#define DOUT 512
#define N_SZ 512
#define M_SZ (B_SZ * T_SZ)  /* 32768 */
#define NCHUNK 16
#define LCHUNK 128          /* T_SZ / NCHUNK */

__device__ __forceinline__ void gload_lds16(const void* g, void* l) {
  __builtin_amdgcn_global_load_lds(
      (const __attribute__((address_space(1))) void*)g,
      (__attribute__((address_space(3))) void*)l, 16, 0, 0);
}

// ---------------- small prep kernels ----------------

__global__ void prep_params(const float* __restrict__ nu_log,
                            const float* __restrict__ theta_log,
                            float2* __restrict__ lam2,
                            float2* __restrict__ lamL2) {
  int n = threadIdx.x;
  if (n < N_SZ) {
    float nu = expf(nu_log[n]);
    float ph = expf(theta_log[n]);
    float la = expf(-nu);
    lam2[n] = make_float2(la * cosf(ph), la * sinf(ph));
    float laL = expf(-nu * (float)LCHUNK);   // |lam|^L
    float phL = ph * (float)LCHUNK;          // exact: *2^7
    lamL2[n] = make_float2(laL * cosf(phL), laL * sinf(phL));
  }
}

// W1[np][d], np in [0,1024): even rows = gamma*B_re[n], odd = gamma*B_im[n], n = np>>1
__global__ void prep_w1(const float* __restrict__ B_re, const float* __restrict__ B_im,
                        const float* __restrict__ gamma_log, f16* __restrict__ W1) {
  int tid = blockIdx.x * 256 + threadIdx.x;   // 1024*512 total
  int np = tid >> 9;
  int d = tid & 511;
  int n = np >> 1;
  float g = expf(gamma_log[n]);
  const float* src = (np & 1) ? B_im : B_re;
  W1[(size_t)np * 512 + d] = (f16)(src[(size_t)n * 512 + d] * g);
}

// W2[j][k], k<512: C_re ; k<1024: -C_im ; else D
__global__ void prep_w2(const float* __restrict__ C_re, const float* __restrict__ C_im,
                        const float* __restrict__ Dm, f16* __restrict__ W2) {
  int k = blockIdx.x * 256 + threadIdx.x;  // 0..1535
  int j = blockIdx.y;                      // 0..511
  float v;
  if (k < 512)       v =  C_re[(size_t)j * 512 + k];
  else if (k < 1024) v = -C_im[(size_t)j * 512 + (k - 512)];
  else               v =  Dm[(size_t)j * 512 + (k - 1024)];
  W2[(size_t)j * 1536 + k] = (f16)v;
}

// fp32 input -> f16, into A2 columns [1024,1536)
__global__ void conv_input(const float* __restrict__ in, f16* __restrict__ A2) {
  int tid = blockIdx.x * 256 + threadIdx.x;  // 32768*512/8 threads
  int m = tid >> 6;
  int d0 = (tid & 63) << 3;
  const float4* p = (const float4*)(in + (size_t)m * DIN + d0);
  float4 a = p[0], b = p[1];
  f16x8 h;
  h[0] = (f16)a.x; h[1] = (f16)a.y; h[2] = (f16)a.z; h[3] = (f16)a.w;
  h[4] = (f16)b.x; h[5] = (f16)b.y; h[6] = (f16)b.z; h[7] = (f16)b.w;
  *(f16x8*)(A2 + (size_t)m * 1536 + 1024 + d0) = h;
}

// ---------------- scan (3 phases, fp32 math, f16 Bu) ----------------

__global__ void scan_a(const f16* __restrict__ Bu, const float2* __restrict__ lam2,
                       float2* __restrict__ S) {
  int tid = blockIdx.x * 256 + threadIdx.x;  // B*NCHUNK*N = 131072
  int n = tid & 511;
  int c = (tid >> 9) & (NCHUNK - 1);
  int b = tid >> 13;
  float2 l = lam2[n];
  const unsigned* bu = (const unsigned*)Bu + (size_t)(b * T_SZ + c * LCHUNK) * 512 + n;
  float sre = 0.f, sim = 0.f;
#pragma unroll 8
  for (int t = 0; t < LCHUNK; ++t) {
    unsigned u = bu[(size_t)t * 512];
    f16x2 h = __builtin_bit_cast(f16x2, u);
    float nre = l.x * sre - l.y * sim + (float)h.x;
    sim = l.x * sim + l.y * sre + (float)h.y;
    sre = nre;
  }
  S[(size_t)(b * NCHUNK + c) * 512 + n] = make_float2(sre, sim);
}

__global__ void scan_b(const float2* __restrict__ S, const float2* __restrict__ lamL2,
                       float2* __restrict__ Carry) {
  int tid = blockIdx.x * 256 + threadIdx.x;  // 8192
  int n = tid & 511;
  int b = tid >> 9;
  float2 lL = lamL2[n];
  float cre = 0.f, cim = 0.f;
  for (int c = 0; c < NCHUNK; ++c) {
    size_t idx = (size_t)(b * NCHUNK + c) * 512 + n;
    Carry[idx] = make_float2(cre, cim);
    float2 s = S[idx];
    float nre = lL.x * cre - lL.y * cim + s.x;
    cim = lL.x * cim + lL.y * cre + s.y;
    cre = nre;
  }
}

__global__ void scan_c(const f16* __restrict__ Bu, const float2* __restrict__ lam2,
                       const float2* __restrict__ Carry, f16* __restrict__ A2) {
  int tid = blockIdx.x * 256 + threadIdx.x;
  int n = tid & 511;
  int c = (tid >> 9) & (NCHUNK - 1);
  int b = tid >> 13;
  float2 l = lam2[n];
  float2 car = Carry[(size_t)(b * NCHUNK + c) * 512 + n];
  float sre = car.x, sim = car.y;
  int m0 = b * T_SZ + c * LCHUNK;
  const unsigned* bu = (const unsigned*)Bu + (size_t)m0 * 512 + n;
  f16* outre = A2 + (size_t)m0 * 1536 + n;
#pragma unroll 4
  for (int t = 0; t < LCHUNK; ++t) {
    unsigned u = bu[(size_t)t * 512];
    f16x2 h = __builtin_bit_cast(f16x2, u);
    float nre = l.x * sre - l.y * sim + (float)h.x;
    sim = l.x * sim + l.y * sre + (float)h.y;
    sre = nre;
    outre[(size_t)t * 1536] = (f16)sre;
    outre[(size_t)t * 1536 + 512] = (f16)sim;
  }
}

// ---------------- f16 MFMA GEMM: C[M][Nn] = A[M][K] * B[Nn][K]^T ----------------
// 128x128 tile, BK=64, 4 waves each owning a 64x64 quadrant.
// A/B fragments use the same bijective (lane,reg)->k mapping, so the result is
// invariant to the true HW k-permutation. C/D layout per guide (m89/m91-verified).

template <typename CT>
__global__ __launch_bounds__(256, 2) void gemm_f16(
    const f16* __restrict__ A, int lda,
    const f16* __restrict__ Bm, int ldb,
    CT* __restrict__ C, int ldc, int K) {
  __shared__ f16 sA[128 * 64];
  __shared__ f16 sB[128 * 64];
  const int tid = threadIdx.x;
  const int lane = tid & 63;
  const int wid = tid >> 6;
  const int m0 = blockIdx.y * 128;
  const int n0 = blockIdx.x * 128;
  const int crow = lane >> 3;        // row within 8-row chunk
  const int ccol = (lane & 7) << 3;  // k-col (8 halfs = 16B)

  f32x4 acc[4][4];
#pragma unroll
  for (int i = 0; i < 4; ++i)
#pragma unroll
    for (int j = 0; j < 4; ++j) acc[i][j] = f32x4{0.f, 0.f, 0.f, 0.f};

  const int ar0 = (wid >> 1) * 64;
  const int bc0 = (wid & 1) * 64;
  const int fr = lane & 15;
  const int fg = lane >> 4;

  for (int kt = 0; kt < K; kt += 64) {
    // stage 32 chunks (16 A + 16 B) of 1024B each via global_load_lds
    for (int i = wid; i < 32; i += 4) {
      int cth = i & 15;
      int row = cth * 8 + crow;
      if (i < 16)
        gload_lds16(A + (size_t)(m0 + row) * lda + kt + ccol, sA + cth * 512);
      else
        gload_lds16(Bm + (size_t)(n0 + row) * ldb + kt + ccol, sB + cth * 512);
    }
    __syncthreads();
#pragma unroll
    for (int ks = 0; ks < 2; ++ks) {
      f16x8 af[4], bfr[4];
#pragma unroll
      for (int mi = 0; mi < 4; ++mi)
        af[mi] = *(const f16x8*)(sA + (ar0 + mi * 16 + fr) * 64 + ks * 32 + fg * 8);
#pragma unroll
      for (int ni = 0; ni < 4; ++ni)
        bfr[ni] = *(const f16x8*)(sB + (bc0 + ni * 16 + fr) * 64 + ks * 32 + fg * 8);
#pragma unroll
      for (int mi = 0; mi < 4; ++mi)
#pragma unroll
        for (int ni = 0; ni < 4; ++ni)
          acc[mi][ni] = __builtin_amdgcn_mfma_f32_16x16x32_f16(af[mi], bfr[ni], acc[mi][ni], 0, 0, 0);
    }
    __syncthreads();
  }

#pragma unroll
  for (int mi = 0; mi < 4; ++mi)
#pragma unroll
    for (int ni = 0; ni < 4; ++ni) {
      int rbase = m0 + ar0 + mi * 16 + fg * 4;
      int col = n0 + bc0 + ni * 16 + fr;
#pragma unroll
      for (int r = 0; r < 4; ++r)
        C[(size_t)(rbase + r) * ldc + col] = (CT)acc[mi][ni][r];
    }
}

// ---------------- launch ----------------

extern "C" void kernel_launch(void* const* d_in, const int* in_sizes, int n_in,
                              void* d_out, int out_size, void* d_ws, size_t ws_size,
                              hipStream_t stream) {
  const float* input = (const float*)d_in[0];
  const float* Dmat = (const float*)d_in[1];
  const float* nu_log = (const float*)d_in[2];
  const float* theta_log = (const float*)d_in[3];
  const float* gamma_log = (const float*)d_in[4];
  const float* B_re = (const float*)d_in[5];
  const float* B_im = (const float*)d_in[6];
  const float* C_re = (const float*)d_in[7];
  const float* C_im = (const float*)d_in[8];
  float* y = (float*)d_out;

  char* ws = (char*)d_ws;
  size_t off = 0;
  auto alloc = [&](size_t bytes) {
    void* p = ws + off;
    off = (off + bytes + 255) & ~(size_t)255;
    return p;
  };
  float2* lam2 = (float2*)alloc(N_SZ * sizeof(float2));
  float2* lamL2 = (float2*)alloc(N_SZ * sizeof(float2));
  f16* W1 = (f16*)alloc((size_t)2 * N_SZ * DIN * 2);        // [1024][512] f16
  f16* W2 = (f16*)alloc((size_t)DOUT * 1536 * 2);           // [512][1536] f16
  f16* A2 = (f16*)alloc((size_t)M_SZ * 1536 * 2);           // [M][re|im|in] f16
  f16* Bu = (f16*)alloc((size_t)M_SZ * 2 * N_SZ * 2);       // [M][1024] f16 (re,im pairs)
  float2* S = (float2*)alloc((size_t)B_SZ * NCHUNK * N_SZ * sizeof(float2));
  float2* Carry = (float2*)alloc((size_t)B_SZ * NCHUNK * N_SZ * sizeof(float2));

  prep_params<<<1, 512, 0, stream>>>(nu_log, theta_log, lam2, lamL2);
  prep_w1<<<2048, 256, 0, stream>>>(B_re, B_im, gamma_log, W1);
  prep_w2<<<dim3(6, 512), 256, 0, stream>>>(C_re, C_im, Dmat, W2);
  conv_input<<<(M_SZ * DIN / 8) / 256, 256, 0, stream>>>(input, A2);

  // Bu = input_f16 @ W1^T   (A = A2 cols [1024,1536), lda=1536)
  gemm_f16<f16><<<dim3(8, 256), 256, 0, stream>>>(A2 + 1024, 1536, W1, 512, Bu, 1024, 512);

  scan_a<<<(B_SZ * NCHUNK * N_SZ) / 256, 256, 0, stream>>>(Bu, lam2, S);
  scan_b<<<(B_SZ * N_SZ) / 256, 256, 0, stream>>>(S, lamL2, Carry);
  scan_c<<<(B_SZ * NCHUNK * N_SZ) / 256, 256, 0, stream>>>(Bu, lam2, Carry, A2);

  // y = [s_re | s_im | in] @ [C_re | -C_im | D]^T
  gemm_f16<float><<<dim3(4, 256), 256, 0, stream>>>(A2, 1536, W2, 1536, y, 512, 1536);
}

// Round 2
// 169.136 us; speedup vs baseline: 1.2119x; 1.2119x over previous
//
#include <hip/hip_runtime.h>
#include <hip/hip_fp16.h>

typedef _Float16 f16;
typedef __attribute__((ext_vector_type(8))) _Float16 f16x8;
typedef __attribute__((ext_vector_type(2))) _Float16 f16x2;
typedef __attribute__((ext_vector_type(4))) float f32x4;

#define B_SZ 16
#define T_SZ 2048
#define DIN 512
#define DOUT 512
#define N_SZ 512
#define M_SZ (B_SZ * T_SZ)  /* 32768 */
#define NCHUNK 16
#define LCHUNK 128          /* T_SZ / NCHUNK */

__device__ __forceinline__ void gload_lds16(const void* g, void* l) {
  __builtin_amdgcn_global_load_lds(
      (const __attribute__((address_space(1))) void*)g,
      (__attribute__((address_space(3))) void*)l, 16, 0, 0);
}

// ---------------- small prep kernels ----------------

__global__ void prep_params(const float* __restrict__ nu_log,
                            const float* __restrict__ theta_log,
                            float2* __restrict__ lam2,
                            float2* __restrict__ lamL2) {
  int n = threadIdx.x;
  if (n < N_SZ) {
    float nu = expf(nu_log[n]);
    float ph = expf(theta_log[n]);
    float la = expf(-nu);
    lam2[n] = make_float2(la * cosf(ph), la * sinf(ph));
    float laL = expf(-nu * (float)LCHUNK);   // |lam|^L
    float phL = ph * (float)LCHUNK;          // exact: *2^7
    lamL2[n] = make_float2(laL * cosf(phL), laL * sinf(phL));
  }
}

// W1[np][d], np in [0,1024): even rows = gamma*B_re[n], odd = gamma*B_im[n], n = np>>1
__global__ void prep_w1(const float* __restrict__ B_re, const float* __restrict__ B_im,
                        const float* __restrict__ gamma_log, f16* __restrict__ W1) {
  int tid = blockIdx.x * 256 + threadIdx.x;   // 1024*512 total
  int np = tid >> 9;
  int d = tid & 511;
  int n = np >> 1;
  float g = expf(gamma_log[n]);
  const float* src = (np & 1) ? B_im : B_re;
  W1[(size_t)np * 512 + d] = (f16)(src[(size_t)n * 512 + d] * g);
}

// W2[j][k], k<512: C_re ; k<1024: -C_im ; else D
__global__ void prep_w2(const float* __restrict__ C_re, const float* __restrict__ C_im,
                        const float* __restrict__ Dm, f16* __restrict__ W2) {
  int k = blockIdx.x * 256 + threadIdx.x;  // 0..1535
  int j = blockIdx.y;                      // 0..511
  float v;
  if (k < 512)       v =  C_re[(size_t)j * 512 + k];
  else if (k < 1024) v = -C_im[(size_t)j * 512 + (k - 512)];
  else               v =  Dm[(size_t)j * 512 + (k - 1024)];
  W2[(size_t)j * 1536 + k] = (f16)v;
}

// fp32 input -> f16, into A2 columns [1024,1536)
__global__ void conv_input(const float* __restrict__ in, f16* __restrict__ A2) {
  int tid = blockIdx.x * 256 + threadIdx.x;  // 32768*512/8 threads
  int m = tid >> 6;
  int d0 = (tid & 63) << 3;
  const float4* p = (const float4*)(in + (size_t)m * DIN + d0);
  float4 a = p[0], b = p[1];
  f16x8 h;
  h[0] = (f16)a.x; h[1] = (f16)a.y; h[2] = (f16)a.z; h[3] = (f16)a.w;
  h[4] = (f16)b.x; h[5] = (f16)b.y; h[6] = (f16)b.z; h[7] = (f16)b.w;
  *(f16x8*)(A2 + (size_t)m * 1536 + 1024 + d0) = h;
}

// ---------------- scan (3 phases, fp32 math, f16 Bu) ----------------

__global__ void scan_a(const f16* __restrict__ Bu, const float2* __restrict__ lam2,
                       float2* __restrict__ S) {
  int tid = blockIdx.x * 256 + threadIdx.x;  // B*NCHUNK*N = 131072
  int n = tid & 511;
  int c = (tid >> 9) & (NCHUNK - 1);
  int b = tid >> 13;
  float2 l = lam2[n];
  const unsigned* bu = (const unsigned*)Bu + (size_t)(b * T_SZ + c * LCHUNK) * 512 + n;
  float sre = 0.f, sim = 0.f;
#pragma unroll 8
  for (int t = 0; t < LCHUNK; ++t) {
    unsigned u = bu[(size_t)t * 512];
    f16x2 h = __builtin_bit_cast(f16x2, u);
    float nre = l.x * sre - l.y * sim + (float)h.x;
    sim = l.x * sim + l.y * sre + (float)h.y;
    sre = nre;
  }
  S[(size_t)(b * NCHUNK + c) * 512 + n] = make_float2(sre, sim);
}

__global__ void scan_b(const float2* __restrict__ S, const float2* __restrict__ lamL2,
                       float2* __restrict__ Carry) {
  int tid = blockIdx.x * 256 + threadIdx.x;  // 8192
  int n = tid & 511;
  int b = tid >> 9;
  float2 lL = lamL2[n];
  float cre = 0.f, cim = 0.f;
  for (int c = 0; c < NCHUNK; ++c) {
    size_t idx = (size_t)(b * NCHUNK + c) * 512 + n;
    Carry[idx] = make_float2(cre, cim);
    float2 s = S[idx];
    float nre = lL.x * cre - lL.y * cim + s.x;
    cim = lL.x * cim + lL.y * cre + s.y;
    cre = nre;
  }
}

__global__ void scan_c(const f16* __restrict__ Bu, const float2* __restrict__ lam2,
                       const float2* __restrict__ Carry, f16* __restrict__ A2) {
  int tid = blockIdx.x * 256 + threadIdx.x;
  int n = tid & 511;
  int c = (tid >> 9) & (NCHUNK - 1);
  int b = tid >> 13;
  float2 l = lam2[n];
  float2 car = Carry[(size_t)(b * NCHUNK + c) * 512 + n];
  float sre = car.x, sim = car.y;
  int m0 = b * T_SZ + c * LCHUNK;
  const unsigned* bu = (const unsigned*)Bu + (size_t)m0 * 512 + n;
  f16* outre = A2 + (size_t)m0 * 1536 + n;
#pragma unroll 4
  for (int t = 0; t < LCHUNK; ++t) {
    unsigned u = bu[(size_t)t * 512];
    f16x2 h = __builtin_bit_cast(f16x2, u);
    float nre = l.x * sre - l.y * sim + (float)h.x;
    sim = l.x * sim + l.y * sre + (float)h.y;
    sre = nre;
    outre[(size_t)t * 1536] = (f16)sre;
    outre[(size_t)t * 1536 + 512] = (f16)sim;
  }
}

// ---------------- 256x256 8-wave MFMA GEMM: C[M][Nn] = A[M][K] * B[Nn][K]^T --------
// BK=64, 2 LDS buffers (128 KiB dynamic), 4 phases/K-tile of 16 MFMA each.
// T2 XOR-swizzle: linear gload_lds dest + inverse-swizzled global source + swizzled
// ds_read address (net logical identity in registers -> same math as R0 kernel).
// Stage for tile t+1 issued at phase 0 of tile t; loads stay in flight across the
// 3 inner phase-barriers; drained by vmcnt(0) at the tile boundary (~1900cy later).

template <typename CT>
__global__ __launch_bounds__(512, 2) void gemm256(
    const f16* __restrict__ A, int lda,
    const f16* __restrict__ Bm, int ldb,
    CT* __restrict__ C, int ldc, int K, int nxt) {
  extern __shared__ f16 smem[];
  f16* sA = smem;                 // 2 bufs x 256x64 halfs
  f16* sB = smem + 2 * 16384;     // 2 bufs x 256x64 halfs

  const int tid = threadIdx.x;
  const int lane = tid & 63;
  const int wid = tid >> 6;
  const int wr = wid >> 2;        // 0..1  (M half)
  const int wc = wid & 3;         // 0..3  (N quarter)
  const int fr = lane & 15;
  const int fg = lane >> 4;       // 0..3
  const int xr = fr & 7;          // read-side swizzle key (row&7 == fr&7)

  // XCD-aware bijective block swizzle (gridDim.x % 8 == 0)
  const int nwg = gridDim.x;
  const int id = blockIdx.x;
  const int swz = (id & 7) * (nwg >> 3) + (id >> 3);
  const int m0 = (swz / nxt) * 256;
  const int n0 = (swz % nxt) * 256;

  // staging geometry: instr i covers rows i*64 + (tid>>3); thread writes phys slot
  // tid&7 of its row, sourcing logical slot (tid&7)^(row&7).
  const int srow = tid >> 3;
  const int scol = ((tid & 7) ^ (srow & 7)) * 8;  // halfs
  const int sdst = wid * 512;                     // halfs within 8KB instr block

  const int NT = K >> 6;

  f32x4 acc[8][4];
#pragma unroll
  for (int i = 0; i < 8; ++i)
#pragma unroll
    for (int j = 0; j < 4; ++j) acc[i][j] = f32x4{0.f, 0.f, 0.f, 0.f};

  auto stage = [&](int t) {
    const int b = t & 1;
    f16* dA = sA + b * 16384 + sdst;
    f16* dB = sB + b * 16384 + sdst;
    const f16* gA = A + (size_t)(m0 + srow) * lda + t * 64 + scol;
    const f16* gB = Bm + (size_t)(n0 + srow) * ldb + t * 64 + scol;
    gload_lds16(gA, dA);
    gload_lds16(gA + (size_t)64 * lda, dA + 4096);
    gload_lds16(gA + (size_t)128 * lda, dA + 8192);
    gload_lds16(gA + (size_t)192 * lda, dA + 12288);
    gload_lds16(gB, dB);
    gload_lds16(gB + (size_t)64 * ldb, dB + 4096);
    gload_lds16(gB + (size_t)128 * ldb, dB + 8192);
    gload_lds16(gB + (size_t)192 * ldb, dB + 12288);
  };

  auto barrier = [&]() {
    __builtin_amdgcn_sched_barrier(0);
    __builtin_amdgcn_s_barrier();
    __builtin_amdgcn_sched_barrier(0);
  };

  // prologue: stage tile 0, drain, sync
  stage(0);
  asm volatile("s_waitcnt vmcnt(0)" ::: "memory");
  barrier();

  f16x8 bf[4][2];
  for (int t = 0; t < NT; ++t) {
    const int b = t & 1;
    const f16* bA = sA + b * 16384;
    const f16* bB = sB + b * 16384;
    if (t + 1 < NT) stage(t + 1);
#pragma unroll
    for (int h = 0; h < 4; ++h) {
      if (h == 0) {
#pragma unroll
        for (int nrep = 0; nrep < 4; ++nrep)
#pragma unroll
          for (int ks = 0; ks < 2; ++ks) {
            int row = wc * 64 + nrep * 16 + fr;
            bf[nrep][ks] =
                *(const f16x8*)(bB + row * 64 + (((ks * 4 + fg) ^ xr) * 8));
          }
      }
      f16x8 af[2][2];
#pragma unroll
      for (int mi = 0; mi < 2; ++mi)
#pragma unroll
        for (int ks = 0; ks < 2; ++ks) {
          int row = wr * 128 + (h * 2 + mi) * 16 + fr;
          af[mi][ks] =
              *(const f16x8*)(bA + row * 64 + (((ks * 4 + fg) ^ xr) * 8));
        }
      __builtin_amdgcn_s_setprio(1);
#pragma unroll
      for (int mi = 0; mi < 2; ++mi)
#pragma unroll
        for (int nrep = 0; nrep < 4; ++nrep)
#pragma unroll
          for (int ks = 0; ks < 2; ++ks)
            acc[h * 2 + mi][nrep] = __builtin_amdgcn_mfma_f32_16x16x32_f16(
                af[mi][ks], bf[nrep][ks], acc[h * 2 + mi][nrep], 0, 0, 0);
      __builtin_amdgcn_s_setprio(0);
      if (h == 3 && t + 1 < NT)
        asm volatile("s_waitcnt vmcnt(0)" ::: "memory");
      barrier();
    }
  }

  // epilogue: C/D layout col=lane&15, row=(lane>>4)*4+r (m89/m91-verified)
#pragma unroll
  for (int mi = 0; mi < 8; ++mi) {
    int rbase = m0 + wr * 128 + mi * 16 + fg * 4;
#pragma unroll
    for (int ni = 0; ni < 4; ++ni) {
      int col = n0 + wc * 64 + ni * 16 + fr;
#pragma unroll
      for (int r = 0; r < 4; ++r)
        C[(size_t)(rbase + r) * ldc + col] = (CT)acc[mi][ni][r];
    }
  }
}

// ---------------- launch ----------------

extern "C" void kernel_launch(void* const* d_in, const int* in_sizes, int n_in,
                              void* d_out, int out_size, void* d_ws, size_t ws_size,
                              hipStream_t stream) {
  const float* input = (const float*)d_in[0];
  const float* Dmat = (const float*)d_in[1];
  const float* nu_log = (const float*)d_in[2];
  const float* theta_log = (const float*)d_in[3];
  const float* gamma_log = (const float*)d_in[4];
  const float* B_re = (const float*)d_in[5];
  const float* B_im = (const float*)d_in[6];
  const float* C_re = (const float*)d_in[7];
  const float* C_im = (const float*)d_in[8];
  float* y = (float*)d_out;

  char* ws = (char*)d_ws;
  size_t off = 0;
  auto alloc = [&](size_t bytes) {
    void* p = ws + off;
    off = (off + bytes + 255) & ~(size_t)255;
    return p;
  };
  float2* lam2 = (float2*)alloc(N_SZ * sizeof(float2));
  float2* lamL2 = (float2*)alloc(N_SZ * sizeof(float2));
  f16* W1 = (f16*)alloc((size_t)2 * N_SZ * DIN * 2);        // [1024][512] f16
  f16* W2 = (f16*)alloc((size_t)DOUT * 1536 * 2);           // [512][1536] f16
  f16* A2 = (f16*)alloc((size_t)M_SZ * 1536 * 2);           // [M][re|im|in] f16
  f16* Bu = (f16*)alloc((size_t)M_SZ * 2 * N_SZ * 2);       // [M][1024] f16 (re,im)
  float2* S = (float2*)alloc((size_t)B_SZ * NCHUNK * N_SZ * sizeof(float2));
  float2* Carry = (float2*)alloc((size_t)B_SZ * NCHUNK * N_SZ * sizeof(float2));

  const int shmem = 131072;
  {
    auto* g16 = gemm256<f16>;
    auto* g32 = gemm256<float>;
    hipFuncSetAttribute((const void*)g16,
                        hipFuncAttributeMaxDynamicSharedMemorySize, shmem);
    hipFuncSetAttribute((const void*)g32,
                        hipFuncAttributeMaxDynamicSharedMemorySize, shmem);
  }

  prep_params<<<1, 512, 0, stream>>>(nu_log, theta_log, lam2, lamL2);
  prep_w1<<<2048, 256, 0, stream>>>(B_re, B_im, gamma_log, W1);
  prep_w2<<<dim3(6, 512), 256, 0, stream>>>(C_re, C_im, Dmat, W2);
  conv_input<<<(M_SZ * DIN / 8) / 256, 256, 0, stream>>>(input, A2);

  // Bu = input_f16 @ W1^T   (A = A2 cols [1024,1536), lda=1536)
  gemm256<f16><<<512, 512, shmem, stream>>>(A2 + 1024, 1536, W1, 512, Bu, 1024, 512, 4);

  scan_a<<<(B_SZ * NCHUNK * N_SZ) / 256, 256, 0, stream>>>(Bu, lam2, S);
  scan_b<<<(B_SZ * N_SZ) / 256, 256, 0, stream>>>(S, lamL2, Carry);
  scan_c<<<(B_SZ * NCHUNK * N_SZ) / 256, 256, 0, stream>>>(Bu, lam2, Carry, A2);

  // y = [s_re | s_im | in] @ [C_re | -C_im | D]^T
  gemm256<float><<<256, 512, shmem, stream>>>(A2, 1536, W2, 1536, y, 512, 1536, 2);
}

// Round 3
// 164.541 us; speedup vs baseline: 1.2458x; 1.0279x over previous
//
#include <hip/hip_runtime.h>
#include <hip/hip_fp16.h>

typedef _Float16 f16;
typedef __attribute__((ext_vector_type(8))) _Float16 f16x8;
typedef __attribute__((ext_vector_type(2))) _Float16 f16x2;
typedef __attribute__((ext_vector_type(16))) float f32x16;

#define B_SZ 16
#define T_SZ 2048
#define DIN 512
#define DOUT 512
#define N_SZ 512
#define M_SZ (B_SZ * T_SZ)  /* 32768 */
#define NCHUNK 16
#define LCHUNK 128          /* T_SZ / NCHUNK */

__device__ __forceinline__ void gload_lds16(const void* g, void* l) {
  __builtin_amdgcn_global_load_lds(
      (const __attribute__((address_space(1))) void*)g,
      (__attribute__((address_space(3))) void*)l, 16, 0, 0);
}

// ---------------- fused prep kernel (grid-range split) ----------------
// blocks [0,2): lam params; [2,2050): W1; [2050,5122): W2; [5122,13314): input->f16

__global__ void prep_all(const float* __restrict__ nu_log,
                         const float* __restrict__ theta_log,
                         const float* __restrict__ gamma_log,
                         const float* __restrict__ B_re, const float* __restrict__ B_im,
                         const float* __restrict__ C_re, const float* __restrict__ C_im,
                         const float* __restrict__ Dm, const float* __restrict__ input,
                         float2* __restrict__ lam2, float2* __restrict__ lamL2,
                         f16* __restrict__ W1, f16* __restrict__ W2,
                         f16* __restrict__ A2) {
  int b = blockIdx.x;
  if (b < 2) {
    int n = b * 256 + threadIdx.x;
    float nu = expf(nu_log[n]);
    float ph = expf(theta_log[n]);
    float la = expf(-nu);
    lam2[n] = make_float2(la * cosf(ph), la * sinf(ph));
    float laL = expf(-nu * (float)LCHUNK);
    float phL = ph * (float)LCHUNK;
    lamL2[n] = make_float2(laL * cosf(phL), laL * sinf(phL));
  } else if (b < 2 + 2048) {
    int tid = (b - 2) * 256 + threadIdx.x;   // 1024*512
    int np = tid >> 9;
    int d = tid & 511;
    int n = np >> 1;
    float g = expf(gamma_log[n]);
    const float* src = (np & 1) ? B_im : B_re;
    W1[(size_t)np * 512 + d] = (f16)(src[(size_t)n * 512 + d] * g);
  } else if (b < 2 + 2048 + 3072) {
    int tid = (b - 2050) * 256 + threadIdx.x;  // 512*1536
    int j = tid / 1536;
    int k = tid - j * 1536;
    float v;
    if (k < 512)       v =  C_re[(size_t)j * 512 + k];
    else if (k < 1024) v = -C_im[(size_t)j * 512 + (k - 512)];
    else               v =  Dm[(size_t)j * 512 + (k - 1024)];
    W2[(size_t)j * 1536 + k] = (f16)v;
  } else {
    int tid = (b - 5122) * 256 + threadIdx.x;  // 32768*512/8
    int m = tid >> 6;
    int d0 = (tid & 63) << 3;
    const float4* p = (const float4*)(input + (size_t)m * DIN + d0);
    float4 a = p[0], c = p[1];
    f16x8 h;
    h[0] = (f16)a.x; h[1] = (f16)a.y; h[2] = (f16)a.z; h[3] = (f16)a.w;
    h[4] = (f16)c.x; h[5] = (f16)c.y; h[6] = (f16)c.z; h[7] = (f16)c.w;
    *(f16x8*)(A2 + (size_t)m * 1536 + 1024 + d0) = h;
  }
}

// ---------------- scan (3 phases, fp32 math, f16 Bu) ----------------

__global__ void scan_a(const f16* __restrict__ Bu, const float2* __restrict__ lam2,
                       float2* __restrict__ S) {
  int tid = blockIdx.x * 256 + threadIdx.x;  // B*NCHUNK*N = 131072
  int n = tid & 511;
  int c = (tid >> 9) & (NCHUNK - 1);
  int b = tid >> 13;
  float2 l = lam2[n];
  const unsigned* bu = (const unsigned*)Bu + (size_t)(b * T_SZ + c * LCHUNK) * 512 + n;
  float sre = 0.f, sim = 0.f;
#pragma unroll 8
  for (int t = 0; t < LCHUNK; ++t) {
    unsigned u = bu[(size_t)t * 512];
    f16x2 h = __builtin_bit_cast(f16x2, u);
    float nre = l.x * sre - l.y * sim + (float)h.x;
    sim = l.x * sim + l.y * sre + (float)h.y;
    sre = nre;
  }
  S[(size_t)(b * NCHUNK + c) * 512 + n] = make_float2(sre, sim);
}

__global__ void scan_b(const float2* __restrict__ S, const float2* __restrict__ lamL2,
                       float2* __restrict__ Carry) {
  int tid = blockIdx.x * 256 + threadIdx.x;  // 8192
  int n = tid & 511;
  int b = tid >> 9;
  float2 lL = lamL2[n];
  float cre = 0.f, cim = 0.f;
  for (int c = 0; c < NCHUNK; ++c) {
    size_t idx = (size_t)(b * NCHUNK + c) * 512 + n;
    Carry[idx] = make_float2(cre, cim);
    float2 s = S[idx];
    float nre = lL.x * cre - lL.y * cim + s.x;
    cim = lL.x * cim + lL.y * cre + s.y;
    cre = nre;
  }
}

__global__ void scan_c(const f16* __restrict__ Bu, const float2* __restrict__ lam2,
                       const float2* __restrict__ Carry, f16* __restrict__ A2) {
  int tid = blockIdx.x * 256 + threadIdx.x;
  int n = tid & 511;
  int c = (tid >> 9) & (NCHUNK - 1);
  int b = tid >> 13;
  float2 l = lam2[n];
  float2 car = Carry[(size_t)(b * NCHUNK + c) * 512 + n];
  float sre = car.x, sim = car.y;
  int m0 = b * T_SZ + c * LCHUNK;
  const unsigned* bu = (const unsigned*)Bu + (size_t)m0 * 512 + n;
  f16* outre = A2 + (size_t)m0 * 1536 + n;
#pragma unroll 4
  for (int t = 0; t < LCHUNK; ++t) {
    unsigned u = bu[(size_t)t * 512];
    f16x2 h = __builtin_bit_cast(f16x2, u);
    float nre = l.x * sre - l.y * sim + (float)h.x;
    sim = l.x * sim + l.y * sre + (float)h.y;
    sre = nre;
    outre[(size_t)t * 1536] = (f16)sre;
    outre[(size_t)t * 1536 + 512] = (f16)sim;
  }
}

// ---------------- 256x256 8-wave 32x32x16-MFMA GEMM: C = A[M][K] * B[Nn][K]^T ----
// BK=64, double-buffered LDS (128 KiB), ONE barrier + ONE vmcnt(0) per K-tile.
// stage(t+1) issues at tile top; drain sits after the full compute region, so the
// issue-to-drain distance (~2600cy) >> HBM latency. Whole tile = one scheduling
// region: compiler pipelines ds_reads under MFMAs with fine-grained lgkmcnt.
// T2 XOR swizzle (slots of 8 halfs, key row&7) = same zero-conflict geometry as R1.
// C/D layout (32x32): col=lane&31, row=(r&3)+8*(r>>2)+4*(lane>>5)  [m74/m101].

template <typename CT>
__global__ __launch_bounds__(512, 2) void gemm256(
    const f16* __restrict__ A, int lda,
    const f16* __restrict__ Bm, int ldb,
    CT* __restrict__ C, int ldc, int K, int nxt) {
  extern __shared__ f16 smem[];  // buf b: A at b*32768, B at b*32768+16384 (halfs)
  const int tid = threadIdx.x;
  const int lane = tid & 63;
  const int wid = tid >> 6;
  const int wr = wid >> 2;        // 0..1
  const int wc = wid & 3;         // 0..3
  const int r32 = lane & 31;
  const int khalf = lane >> 5;    // 0..1
  const int key = r32 & 7;

  const int nwg = gridDim.x;
  const int id = blockIdx.x;
  const int swz = (id & 7) * (nwg >> 3) + (id >> 3);
  const int m0 = (swz / nxt) * 256;
  const int n0 = (swz % nxt) * 256;

  const int srow = tid >> 3;                      // 64 rows per instr
  const int scol = ((tid & 7) ^ (srow & 7)) * 8;  // inverse-swizzled source col
  const int NT = K >> 6;

  f32x16 acc[4][2];
#pragma unroll
  for (int i = 0; i < 4; ++i)
#pragma unroll
    for (int j = 0; j < 2; ++j)
#pragma unroll
      for (int r = 0; r < 16; ++r) acc[i][j][r] = 0.f;

  auto stage = [&](int t) {
    f16* base = smem + (t & 1) * 32768;
    f16* dst = base + tid * 8;
    const f16* gA = A + (size_t)(m0 + srow) * lda + t * 64 + scol;
    const f16* gB = Bm + (size_t)(n0 + srow) * ldb + t * 64 + scol;
#pragma unroll
    for (int i = 0; i < 4; ++i) {
      gload_lds16(gA + (size_t)(i * 64) * lda, dst + i * 4096);
      gload_lds16(gB + (size_t)(i * 64) * ldb, dst + 16384 + i * 4096);
    }
  };

  stage(0);
  asm volatile("s_waitcnt vmcnt(0)" ::: "memory");
  __builtin_amdgcn_sched_barrier(0);
  __builtin_amdgcn_s_barrier();
  __builtin_amdgcn_sched_barrier(0);

  for (int t = 0; t < NT; ++t) {
    if (t + 1 < NT) stage(t + 1);
    const f16* bA = smem + (t & 1) * 32768;
    const f16* bB = bA + 16384;
#pragma unroll
    for (int ks = 0; ks < 4; ++ks) {
      const int so = ((ks * 2 + khalf) ^ key) * 8;
      f16x8 af[4], bf[2];
#pragma unroll
      for (int mi = 0; mi < 4; ++mi)
        af[mi] = *(const f16x8*)(bA + (wr * 128 + mi * 32 + r32) * 64 + so);
#pragma unroll
      for (int ni = 0; ni < 2; ++ni)
        bf[ni] = *(const f16x8*)(bB + (wc * 64 + ni * 32 + r32) * 64 + so);
#pragma unroll
      for (int mi = 0; mi < 4; ++mi)
#pragma unroll
        for (int ni = 0; ni < 2; ++ni)
          acc[mi][ni] = __builtin_amdgcn_mfma_f32_32x32x16_f16(
              af[mi], bf[ni], acc[mi][ni], 0, 0, 0);
    }
    asm volatile("s_waitcnt vmcnt(0)" ::: "memory");
    __builtin_amdgcn_sched_barrier(0);
    __builtin_amdgcn_s_barrier();
    __builtin_amdgcn_sched_barrier(0);
  }

#pragma unroll
  for (int mi = 0; mi < 4; ++mi)
#pragma unroll
    for (int ni = 0; ni < 2; ++ni)
#pragma unroll
      for (int r = 0; r < 16; ++r) {
        int row = m0 + wr * 128 + mi * 32 + (r & 3) + ((r >> 2) * 8) + khalf * 4;
        int col = n0 + wc * 64 + ni * 32 + r32;
        C[(size_t)row * ldc + col] = (CT)acc[mi][ni][r];
      }
}

// ---------------- launch ----------------

extern "C" void kernel_launch(void* const* d_in, const int* in_sizes, int n_in,
                              void* d_out, int out_size, void* d_ws, size_t ws_size,
                              hipStream_t stream) {
  const float* input = (const float*)d_in[0];
  const float* Dmat = (const float*)d_in[1];
  const float* nu_log = (const float*)d_in[2];
  const float* theta_log = (const float*)d_in[3];
  const float* gamma_log = (const float*)d_in[4];
  const float* B_re = (const float*)d_in[5];
  const float* B_im = (const float*)d_in[6];
  const float* C_re = (const float*)d_in[7];
  const float* C_im = (const float*)d_in[8];
  float* y = (float*)d_out;

  char* ws = (char*)d_ws;
  size_t off = 0;
  auto alloc = [&](size_t bytes) {
    void* p = ws + off;
    off = (off + bytes + 255) & ~(size_t)255;
    return p;
  };
  float2* lam2 = (float2*)alloc(N_SZ * sizeof(float2));
  float2* lamL2 = (float2*)alloc(N_SZ * sizeof(float2));
  f16* W1 = (f16*)alloc((size_t)2 * N_SZ * DIN * 2);        // [1024][512] f16
  f16* W2 = (f16*)alloc((size_t)DOUT * 1536 * 2);           // [512][1536] f16
  f16* A2 = (f16*)alloc((size_t)M_SZ * 1536 * 2);           // [M][re|im|in] f16
  f16* Bu = (f16*)alloc((size_t)M_SZ * 2 * N_SZ * 2);       // [M][1024] f16 (re,im)
  float2* S = (float2*)alloc((size_t)B_SZ * NCHUNK * N_SZ * sizeof(float2));
  float2* Carry = (float2*)alloc((size_t)B_SZ * NCHUNK * N_SZ * sizeof(float2));

  const int shmem = 131072;
  {
    auto* g16 = gemm256<f16>;
    auto* g32 = gemm256<float>;
    hipFuncSetAttribute((const void*)g16,
                        hipFuncAttributeMaxDynamicSharedMemorySize, shmem);
    hipFuncSetAttribute((const void*)g32,
                        hipFuncAttributeMaxDynamicSharedMemorySize, shmem);
  }

  prep_all<<<13314, 256, 0, stream>>>(nu_log, theta_log, gamma_log, B_re, B_im,
                                      C_re, C_im, Dmat, input, lam2, lamL2, W1, W2, A2);

  // Bu = input_f16 @ W1^T   (A = A2 cols [1024,1536), lda=1536)
  gemm256<f16><<<512, 512, shmem, stream>>>(A2 + 1024, 1536, W1, 512, Bu, 1024, 512, 4);

  scan_a<<<(B_SZ * NCHUNK * N_SZ) / 256, 256, 0, stream>>>(Bu, lam2, S);
  scan_b<<<(B_SZ * N_SZ) / 256, 256, 0, stream>>>(S, lamL2, Carry);
  scan_c<<<(B_SZ * NCHUNK * N_SZ) / 256, 256, 0, stream>>>(Bu, lam2, Carry, A2);

  // y = [s_re | s_im | in] @ [C_re | -C_im | D]^T
  gemm256<float><<<256, 512, shmem, stream>>>(A2, 1536, W2, 1536, y, 512, 1536, 2);
}